// Round 12
// baseline (745.344 us; speedup 1.0000x reference)
//
#include <hip/hip_runtime.h>
#include <hip/hip_bf16.h>

#define N_NODES 10000
#define NE 160000
#define CAP 96              // direct bucket capacity per (slot,node)
#define SQRT_C 0.1f
#define CC 0.01f
#define EPS 1e-15f
#define MAXNORM ((1.0f - 4e-3f) / SQRT_C)   // geoopt projx boundary, 9.96
#define REP 16              // MEASUREMENT ROUND 2: dur = cold + 15*warm per kernel

// fast transcendentals (bounded, sign-known args; ~1 ulp worse than libm)
__device__ __forceinline__ float fexp(float x) { return __expf(x); }
__device__ __forceinline__ float ftanh_pos(float x) {      // x >= 0
    return 1.0f - 2.0f / (__expf(2.0f * x) + 1.0f);
}
__device__ __forceinline__ float fatanh01(float t) {       // 0 <= t < 1
    return 0.5f * __logf((1.0f + t) / (1.0f - t));
}

// dual-dtype load: harness may hand float arrays as bf16 or float32
__device__ __forceinline__ float ldf(const void* p, int i, int isbf) {
    return isbf ? __bfloat162float(((const __hip_bfloat16*)p)[i])
                : ((const float*)p)[i];
}

__device__ __forceinline__ int sniff_wave(const void* emb, int tid) {
    unsigned wv = ((const unsigned*)emb)[tid & 63];
    unsigned ex = (wv >> 7) & 0xFFu;
    unsigned long long m = __ballot(ex >= 116u && ex <= 133u);
    return (__popcll(m) >= 32) ? 1 : 0;
}

// ---------- wave-wide helpers (wave64) ----------
__device__ __forceinline__ float wsum(float v) {
#pragma unroll
    for (int off = 32; off > 0; off >>= 1) v += __shfl_xor(v, off, 64);
    return v;
}
__device__ __forceinline__ float wmax(float v) {
#pragma unroll
    for (int off = 32; off > 0; off >>= 1) v = fmaxf(v, __shfl_xor(v, off, 64));
    return v;
}

// DPP wave64 sum (VALU pipe; no ds_bpermute). Total in lane 63 -> readlane.
__device__ __forceinline__ float dpp_wsum(float x) {
    int t;
    t = __builtin_amdgcn_update_dpp(0, __float_as_int(x), 0x111, 0xF, 0xF, true); // row_shr:1
    x += __int_as_float(t);
    t = __builtin_amdgcn_update_dpp(0, __float_as_int(x), 0x112, 0xF, 0xF, true); // row_shr:2
    x += __int_as_float(t);
    t = __builtin_amdgcn_update_dpp(0, __float_as_int(x), 0x114, 0xF, 0xE, true); // row_shr:4
    x += __int_as_float(t);
    t = __builtin_amdgcn_update_dpp(0, __float_as_int(x), 0x118, 0xF, 0xC, true); // row_shr:8
    x += __int_as_float(t);
    t = __builtin_amdgcn_update_dpp(0, __float_as_int(x), 0x142, 0xA, 0xF, true); // row_bcast:15
    x += __int_as_float(t);
    t = __builtin_amdgcn_update_dpp(0, __float_as_int(x), 0x143, 0xC, 0xF, true); // row_bcast:31
    x += __int_as_float(t);
    return __int_as_float(__builtin_amdgcn_readlane(__float_as_int(x), 63));
}

// ---------- kernel 1a: node features + weights (REP-inflated) ----------
__global__ __launch_bounds__(256) void feat_weights(const void* __restrict__ emb,
                                                    const void* __restrict__ att_i,
                                                    const void* __restrict__ att_j,
                                                    const void* __restrict__ w1g,
                                                    const void* __restrict__ b1g,
                                                    const void* __restrict__ w2g,
                                                    const void* __restrict__ b2g,
                                                    float* __restrict__ xt,
                                                    float* __restrict__ ai,
                                                    float* __restrict__ aj,
                                                    int* __restrict__ flag,
                                                    float* __restrict__ wf1t,
                                                    float* __restrict__ wf2t,
                                                    float* __restrict__ hb1f,
                                                    float* __restrict__ hb2f,
                                                    float* __restrict__ hbn2,
                                                    int zr) {
    __shared__ int sflag;
    int tid = threadIdx.x;
    int w = tid >> 6, lane = tid & 63;
    if (tid < 64) { int s = sniff_wave(emb, tid); if (tid == 0) sflag = s; }
    __syncthreads();
    int isbf = sflag;
    if (blockIdx.x < 2500) {
        int t = blockIdx.x * 256 + tid;            // 10000*64 threads exact
        int node = t >> 6;
#pragma unroll 1
        for (int r = 0; r < REP; ++r) {
            int ro = r * zr;
            float u = ldf(emb, node * 64 + lane + ro, isbf);
            float n = fmaxf(sqrtf(wsum(u * u)), EPS);
            float th = ftanh_pos(SQRT_C * n);
            float x0 = th / (SQRT_C * n) * u;
            float x0n = th / SQRT_C;
            if (x0n > MAXNORM) { x0 *= MAXNORM / x0n; x0n = MAXNORM; }
            float tc = fminf(SQRT_C * x0n, 1.0f - 1e-7f);
            float xv = fatanh01(tc) / (SQRT_C * x0n) * x0;
            xt[node * 64 + lane + ro] = xv;
            float pi = xv * ldf(att_i, lane + ro, isbf);
            float pj = xv * ldf(att_j, lane + ro, isbf);
#pragma unroll
            for (int off = 8; off > 0; off >>= 1) {
                pi += __shfl_xor(pi, off, 64);
                pj += __shfl_xor(pj, off, 64);
            }
            if ((lane & 15) == 0) {
                ai[node * 4 + (lane >> 4) + ro] = pi;
                aj[node * 4 + (lane >> 4) + ro] = pj;
            }
        }
    } else {
        if (tid == 0) *flag = isbf;
#pragma unroll 1
        for (int r = 0; r < REP; ++r) {
            int ro = r * zr;
            for (int i = tid; i < 1024; i += 256) {
                int o = i >> 4, c = i & 15;
                wf1t[c * 64 + o + ro] = ldf(w1g, i + ro, isbf);
            }
            for (int i = tid; i < 4096; i += 256) {
                int o = i >> 6, c = i & 63;
                wf2t[c * 64 + o + ro] = ldf(w2g, i + ro, isbf);
            }
            if (w < 2) {
                const void* bg = w ? b2g : b1g;
                float b = ldf(bg, lane + ro, isbf);
                float n = fmaxf(sqrtf(wsum(b * b)), EPS);
                float th = ftanh_pos(SQRT_C * n);
                float hv = th / (SQRT_C * n) * b;
                float hn = th / SQRT_C;
                if (hn > MAXNORM) { hv *= MAXNORM / hn; hn = MAXNORM; }
                (w ? hb2f : hb1f)[lane + ro] = hv;
                if (lane == 0) hbn2[w + ro] = hn * hn;
            }
        }
    }
}

// ---------- kernel 1b: edge scatter (NOT idempotent -> not inflated) ----------
__global__ __launch_bounds__(256) void scatter_k(const int* __restrict__ ei,
                                                 int* __restrict__ cnt,
                                                 unsigned short* __restrict__ bucket,
                                                 int* __restrict__ ovf_cnt,
                                                 unsigned* __restrict__ ovf) {
    int tid = threadIdx.x;
    int e0 = blockIdx.x * 512 + tid;               // 313 blocks x 512 edges
#pragma unroll
    for (int q = 0; q < 2; ++q) {
        int e = e0 + q * 256;
        if (e >= NE) break;
        int s0 = ei[3 * 2 * NE + e], d0 = ei[3 * 2 * NE + NE + e];
        int s1 = ei[7 * 2 * NE + e], d1 = ei[7 * 2 * NE + NE + e];
        int i0 = s0, i1 = N_NODES + s1;
        int p0 = atomicAdd(&cnt[i0], 1);
        int p1 = atomicAdd(&cnt[i1], 1);
        if (p0 < CAP) bucket[i0 * CAP + p0] = (unsigned short)d0;
        else {
            int oi = atomicAdd(ovf_cnt, 1);
            ovf[oi] = (0u << 28) | ((unsigned)s0 << 14) | (unsigned)d0;
        }
        if (p1 < CAP) bucket[i1 * CAP + p1] = (unsigned short)d1;
        else {
            int oi = atomicAdd(ovf_cnt, 1);
            ovf[oi] = (1u << 28) | ((unsigned)s1 << 14) | (unsigned)d1;
        }
    }
}

// ---------- kernel 2: per-node softmax + aggregation (REP-inflated) ----------
// sup_t NODE-MAJOR [20000][16]
__global__ __launch_bounds__(256) void node_agg(const int* __restrict__ cnt,
                                                const unsigned short* __restrict__ bucket,
                                                const int* __restrict__ ovf_cnt,
                                                const unsigned* __restrict__ ovf,
                                                const float* __restrict__ ai,
                                                const float* __restrict__ aj,
                                                const float* __restrict__ xt,
                                                float* __restrict__ sup_t,
                                                int zr) {
    __shared__ float wlds[4][64 * 4];
    __shared__ int dlds[4][64];
    int w = threadIdx.x >> 6, lane = threadIdx.x & 63;
    int idx = blockIdx.x * 4 + w;          // grid exact: 20000 waves
    int slot = (idx >= N_NODES) ? 1 : 0;
    int n = idx - slot * N_NODES;
    int hh = lane >> 4;

#pragma unroll 1
    for (int r = 0; r < REP; ++r) {
        int ro = r * zr;
        int deg = cnt[idx + ro];
        int start = idx * CAP + ro;

        float4 ai4 = *(const float4*)&ai[n * 4 + ro];
        float4 aj4n = *(const float4*)&aj[n * 4 + ro];
        float ain[4] = {ai4.x, ai4.y, ai4.z, ai4.w};
        float ajn[4] = {aj4n.x, aj4n.y, aj4n.z, aj4n.w};
        float acc;

        if (deg <= 63) {
            bool act = (lane <= deg);          // lane==deg is the self-loop
            int d = (lane < deg) ? (int)bucket[start + lane] : n;
            float4 a4 = act ? *(const float4*)&aj[d * 4] : make_float4(0.f, 0.f, 0.f, 0.f);
            float ajv[4] = {a4.x, a4.y, a4.z, a4.w};
            float eh[4];
#pragma unroll
            for (int h = 0; h < 4; ++h) {
                float a = ain[h] + ajv[h];
                a = (a < 0.0f) ? 0.2f * a : a;
                eh[h] = act ? fexp(a) : 0.0f;
            }
            float sh[4];
#pragma unroll
            for (int h = 0; h < 4; ++h) sh[h] = wsum(eh[h]);
#pragma unroll
            for (int h = 0; h < 4; ++h)
                wlds[w][lane * 4 + h] = eh[h] * (0.25f / (sh[h] + 1e-16f));
            dlds[w][lane] = d;
            int m = deg + 1;
            float s0 = 0.f, s1 = 0.f, s2 = 0.f, s3 = 0.f;
            float s4 = 0.f, s5 = 0.f, s6 = 0.f, s7 = 0.f;
            int e = 0;
            for (; e + 8 <= m; e += 8) {
                int d0 = dlds[w][e],     d1 = dlds[w][e + 1];
                int d2 = dlds[w][e + 2], d3 = dlds[w][e + 3];
                int d4 = dlds[w][e + 4], d5 = dlds[w][e + 5];
                int d6 = dlds[w][e + 6], d7 = dlds[w][e + 7];
                float w0 = wlds[w][(e + 0) * 4 + hh], w1 = wlds[w][(e + 1) * 4 + hh];
                float w2 = wlds[w][(e + 2) * 4 + hh], w3 = wlds[w][(e + 3) * 4 + hh];
                float w4 = wlds[w][(e + 4) * 4 + hh], w5 = wlds[w][(e + 5) * 4 + hh];
                float w6 = wlds[w][(e + 6) * 4 + hh], w7 = wlds[w][(e + 7) * 4 + hh];
                s0 = fmaf(w0, xt[d0 * 64 + lane], s0);
                s1 = fmaf(w1, xt[d1 * 64 + lane], s1);
                s2 = fmaf(w2, xt[d2 * 64 + lane], s2);
                s3 = fmaf(w3, xt[d3 * 64 + lane], s3);
                s4 = fmaf(w4, xt[d4 * 64 + lane], s4);
                s5 = fmaf(w5, xt[d5 * 64 + lane], s5);
                s6 = fmaf(w6, xt[d6 * 64 + lane], s6);
                s7 = fmaf(w7, xt[d7 * 64 + lane], s7);
            }
            for (; e + 4 <= m; e += 4) {
                int d0 = dlds[w][e],     d1 = dlds[w][e + 1];
                int d2 = dlds[w][e + 2], d3 = dlds[w][e + 3];
                float w0 = wlds[w][(e + 0) * 4 + hh], w1 = wlds[w][(e + 1) * 4 + hh];
                float w2 = wlds[w][(e + 2) * 4 + hh], w3 = wlds[w][(e + 3) * 4 + hh];
                s0 = fmaf(w0, xt[d0 * 64 + lane], s0);
                s1 = fmaf(w1, xt[d1 * 64 + lane], s1);
                s2 = fmaf(w2, xt[d2 * 64 + lane], s2);
                s3 = fmaf(w3, xt[d3 * 64 + lane], s3);
            }
            for (; e < m; ++e)
                s0 = fmaf(wlds[w][e * 4 + hh], xt[dlds[w][e] * 64 + lane], s0);
            acc = ((s0 + s1) + (s2 + s3)) + ((s4 + s5) + (s6 + s7));
        } else {
            // slow path (rare): strided over bucket + overflow scan, max-shifted
            int bdeg = (deg < CAP) ? deg : CAP;
            int tov = (deg > CAP) ? *ovf_cnt : 0;
            float mh[4];
#pragma unroll
            for (int h = 0; h < 4; ++h) {
                float a = ain[h] + ajn[h];
                mh[h] = (a < 0.0f) ? 0.2f * a : a;
            }
            for (int e = lane; e < bdeg; e += 64) {
                int d = bucket[start + e];
#pragma unroll
                for (int h = 0; h < 4; ++h) {
                    float a = ain[h] + aj[d * 4 + h];
                    a = (a < 0.0f) ? 0.2f * a : a;
                    mh[h] = fmaxf(mh[h], a);
                }
            }
            for (int k = lane; k < tov; k += 64) {
                unsigned pe = ovf[k];
                if ((int)(pe >> 28) == slot && (int)((pe >> 14) & 0x3FFFu) == n) {
                    int d = pe & 0x3FFFu;
#pragma unroll
                    for (int h = 0; h < 4; ++h) {
                        float a = ain[h] + aj[d * 4 + h];
                        a = (a < 0.0f) ? 0.2f * a : a;
                        mh[h] = fmaxf(mh[h], a);
                    }
                }
            }
#pragma unroll
            for (int h = 0; h < 4; ++h) mh[h] = wmax(mh[h]);
            float sh[4] = {0.f, 0.f, 0.f, 0.f};
            if (lane == 0) {
#pragma unroll
                for (int h = 0; h < 4; ++h) {
                    float a = ain[h] + ajn[h];
                    a = (a < 0.0f) ? 0.2f * a : a;
                    sh[h] = fexp(a - mh[h]);
                }
            }
            for (int e = lane; e < bdeg; e += 64) {
                int d = bucket[start + e];
#pragma unroll
                for (int h = 0; h < 4; ++h) {
                    float a = ain[h] + aj[d * 4 + h];
                    a = (a < 0.0f) ? 0.2f * a : a;
                    sh[h] += fexp(a - mh[h]);
                }
            }
            for (int k = lane; k < tov; k += 64) {
                unsigned pe = ovf[k];
                if ((int)(pe >> 28) == slot && (int)((pe >> 14) & 0x3FFFu) == n) {
                    int d = pe & 0x3FFFu;
#pragma unroll
                    for (int h = 0; h < 4; ++h) {
                        float a = ain[h] + aj[d * 4 + h];
                        a = (a < 0.0f) ? 0.2f * a : a;
                        sh[h] += fexp(a - mh[h]);
                    }
                }
            }
#pragma unroll
            for (int h = 0; h < 4; ++h) sh[h] = wsum(sh[h]);
            float scale[4];
#pragma unroll
            for (int h = 0; h < 4; ++h) scale[h] = 0.25f / (sh[h] + 1e-16f);
            float aih = ain[hh], mhh = mh[hh], sch = scale[hh];
            float aself = aih + ajn[hh];
            aself = (aself < 0.0f) ? 0.2f * aself : aself;
            acc = fexp(aself - mhh) * sch * xt[n * 64 + lane];
            for (int e = 0; e < bdeg; ++e) {
                int d = bucket[start + e];
                float a = aih + aj[d * 4 + hh];
                a = (a < 0.0f) ? 0.2f * a : a;
                acc = fmaf(fexp(a - mhh) * sch, xt[d * 64 + lane], acc);
            }
            for (int k = 0; k < tov; ++k) {
                unsigned pe = ovf[k];
                if ((int)(pe >> 28) == slot && (int)((pe >> 14) & 0x3FFFu) == n) {
                    int d = pe & 0x3FFFu;
                    float a = aih + aj[d * 4 + hh];
                    a = (a < 0.0f) ? 0.2f * a : a;
                    acc = fmaf(fexp(a - mhh) * sch, xt[d * 64 + lane], acc);
                }
            }
        }
        acc += __shfl_xor(acc, 16, 64);        // head mean (x0.25 in scale)
        acc += __shfl_xor(acc, 32, 64);
        if (lane < 16) sup_t[idx * 16 + lane + ro] = acc;   // node-major
    }
}

// ---------- kernel 3: DPP hyperbolic head (REP-inflated, weights in-loop) ----------
__global__ __launch_bounds__(256) void final_stage(const float* __restrict__ sup_t,
                                                   const float* __restrict__ wf1t,
                                                   const float* __restrict__ wf2t,
                                                   const float* __restrict__ hb1f,
                                                   const float* __restrict__ hb2f,
                                                   const float* __restrict__ hbn2,
                                                   const int* __restrict__ flag,
                                                   void* __restrict__ outv,
                                                   int zr) {
    __shared__ float vz[4][80];            // per-wave scratch: v[16] | z2[64]
    int tid = threadIdx.x, w = tid >> 6, lane = tid & 63;
    float* vbuf = vz[w];
    float* zbuf = vz[w] + 16;
    int nb = (blockIdx.x * 4 + w) * 4;     // 4 consecutive nodes per wave
    int isbf = *flag;

#pragma unroll 1
    for (int r = 0; r < REP; ++r) {
        int ro = r * zr;
        // weights INSIDE the rep so the slope includes the full warm path
        float w2r[64];
#pragma unroll
        for (int c = 0; c < 64; ++c) w2r[c] = wf2t[c * 64 + lane + ro];
        float w1r[16];
#pragma unroll
        for (int c = 0; c < 16; ++c) w1r[c] = wf1t[c * 64 + lane + ro];
        float hb1 = hb1f[lane + ro], hb2v = hb2f[lane + ro];
        float y2a = hbn2[0 + ro], y2b = hbn2[1 + ro];

        float vls[4];
#pragma unroll
        for (int k = 0; k < 4; ++k)
            vls[k] = (lane < 16) ? sup_t[(nb + k) * 16 + lane + ro] : 0.0f;

#pragma unroll 1
        for (int k = 0; k < 4; ++k) {
            float vl = vls[k];
            if (lane < 16) vbuf[lane] = vl;
            float n2 = dpp_wsum(vl * vl);
            float n = fmaxf(sqrtf(n2), EPS);
            float th0 = ftanh_pos(SQRT_C * n);
            float s0 = th0 / (SQRT_C * n);
            float x0n = th0 / SQRT_C;
            if (x0n > MAXNORM) { s0 *= MAXNORM / x0n; x0n = MAXNORM; }

            float a1 = 0.f;
#pragma unroll
            for (int j = 0; j < 4; ++j) {
                const float4 vq = *(const float4*)&vbuf[j * 4];
                a1 = fmaf(w1r[4 * j + 0], vq.x, a1);
                a1 = fmaf(w1r[4 * j + 1], vq.y, a1);
                a1 = fmaf(w1r[4 * j + 2], vq.z, a1);
                a1 = fmaf(w1r[4 * j + 3], vq.w, a1);
            }
            a1 *= s0;

            float mxn2 = dpp_wsum(a1 * a1);
            float mxhb = dpp_wsum(a1 * hb1);
            float xn = fmaxf(x0n, EPS);
            float mxn = fmaxf(sqrtf(mxn2), EPS);
            float t = fminf(SQRT_C * xn, 1.0f - 1e-7f);
            float th = ftanh_pos(mxn / xn * fatanh01(t));
            float rs = th / (mxn * SQRT_C);
            float rn = th / SQRT_C;
            if (mxn2 == 0.0f) { rs = 0.f; rn = 0.f; }
            if (rn > MAXNORM) { rs *= MAXNORM / rn; rn = MAXNORM; }
            float xy = rs * mxhb;
            float x2 = rn * rn;
            float A = 1.0f + 2.0f * CC * xy + CC * y2a;
            float B = 1.0f - CC * x2;
            float rden = 1.0f / fmaxf(1.0f + 2.0f * CC * xy + CC * CC * x2 * y2a, EPS);
            float z = (A * rs * a1 + B * hb1) * rden;

            float zn2 = dpp_wsum(z * z);
            float zn = fmaxf(sqrtf(zn2), EPS);
            float sc = (zn > MAXNORM) ? MAXNORM / zn : 1.0f;
            float z1n = fminf(zn, MAXNORM);
            float lg = fatanh01(fminf(SQRT_C * z1n, 1.0f - 1e-7f)) / (SQRT_C * z1n) * sc;
            float u = lg * z;
            u = u / (1.0f + __expf(-u));

            float un2 = dpp_wsum(u * u);
            float un = fmaxf(sqrtf(un2), EPS);
            float th2 = ftanh_pos(SQRT_C * un);
            float s2 = th2 / (SQRT_C * un);
            float z2n = th2 / SQRT_C;
            if (z2n > MAXNORM) { s2 *= MAXNORM / z2n; z2n = MAXNORM; }
            float z2 = u * s2;

            zbuf[lane] = z2;
            float a2 = 0.f;
#pragma unroll
            for (int j = 0; j < 16; ++j) {
                const float4 zq = *(const float4*)&zbuf[j * 4];
                a2 = fmaf(w2r[4 * j + 0], zq.x, a2);
                a2 = fmaf(w2r[4 * j + 1], zq.y, a2);
                a2 = fmaf(w2r[4 * j + 2], zq.z, a2);
                a2 = fmaf(w2r[4 * j + 3], zq.w, a2);
            }

            float pn2 = dpp_wsum(a2 * a2);
            float ph2 = dpp_wsum(a2 * hb2v);
            float xnb = fmaxf(z2n, EPS);
            float mxnb = fmaxf(sqrtf(pn2), EPS);
            float tb = fminf(SQRT_C * xnb, 1.0f - 1e-7f);
            float thb = ftanh_pos(mxnb / xnb * fatanh01(tb));
            float rsb = thb / (mxnb * SQRT_C);
            float rnb = thb / SQRT_C;
            if (pn2 == 0.0f) { rsb = 0.f; rnb = 0.f; }
            if (rnb > MAXNORM) { rsb *= MAXNORM / rnb; rnb = MAXNORM; }
            float xyb = rsb * ph2;
            float x2b = rnb * rnb;
            float Ab = 1.0f + 2.0f * CC * xyb + CC * y2b;
            float Bb = 1.0f - CC * x2b;
            float rdenb = 1.0f / fmaxf(1.0f + 2.0f * CC * xyb + CC * CC * x2b * y2b, EPS);
            float zf = (Ab * rsb * a2 + Bb * hb2v) * rdenb;
            float zf2 = dpp_wsum(zf * zf);
            float znf = fmaxf(sqrtf(zf2), EPS);
            float s4 = (znf > MAXNORM) ? MAXNORM / znf : 1.0f;
            float val = zf * s4;

            if (isbf) ((__hip_bfloat16*)outv)[(nb + k) * 64 + lane + ro] = __float2bfloat16(val);
            else      ((float*)outv)[(nb + k) * 64 + lane + ro] = val;
        }
    }
}

extern "C" void kernel_launch(void* const* d_in, const int* in_sizes, int n_in,
                              void* d_out, int out_size, void* d_ws, size_t ws_size,
                              hipStream_t stream) {
    // setup_inputs order: history_graphs(0, unused), edge_index(1), emb(2),
    //                     att_i(3), att_j(4), w1(5), b1(6), w2(7), b2(8)
    const int* ei = (const int*)d_in[1];
    const void* emb   = d_in[2];
    const void* att_i = d_in[3];
    const void* att_j = d_in[4];
    const void* w1 = d_in[5];
    const void* b1 = d_in[6];
    const void* w2 = d_in[7];
    const void* b2 = d_in[8];

    float* ws = (float*)d_ws;
    float* xt    = ws;                                // [10000][64]: 0..640000
    float* ai    = ws + 640000;                       // [10000][4]
    float* aj    = ws + 680000;                       // [10000][4]
    float* sup_t = ws + 720000;                       // [20000][16]: ..1040000
    int* cnt     = (int*)(ws + 1040000);              // [2][10000]: ..1060000
    int* ovf_cnt = (int*)(ws + 1060000);              // 1 int (memset covers it)
    unsigned short* bucket = (unsigned short*)(ws + 1060032); // ..2020032
    unsigned* ovf = (unsigned*)(ws + 2020032);        // [320000]: ..2340032
    int* flag     = (int*)(ws + 2340032);
    float* wf1t = ws + 2340064;                       // [16][64]: ..2341088
    float* wf2t = ws + 2341088;                       // [64][64]: ..2345184
    float* hb1f = ws + 2345184;                       // [64]
    float* hb2f = ws + 2345248;                       // [64]
    float* hbn2 = ws + 2345312;                       // [2]

    int zr = 0;   // runtime zero: defeats LICM/DCE of the REP loops

    hipMemsetAsync((void*)cnt, 0, (2 * N_NODES + 8) * sizeof(int), stream);
    hipLaunchKernelGGL(feat_weights, dim3(2501), dim3(256), 0, stream,
                       emb, att_i, att_j, w1, b1, w2, b2,
                       xt, ai, aj, flag, wf1t, wf2t, hb1f, hb2f, hbn2, zr);
    hipLaunchKernelGGL(scatter_k, dim3(313), dim3(256), 0, stream,
                       ei, cnt, bucket, ovf_cnt, ovf);
    hipLaunchKernelGGL(node_agg, dim3(5000), dim3(256), 0, stream,
                       cnt, bucket, ovf_cnt, ovf, ai, aj, xt, sup_t, zr);
    hipLaunchKernelGGL(final_stage, dim3(1250), dim3(256), 0, stream,
                       sup_t, wf1t, wf2t, hb1f, hb2f, hbn2, flag, d_out, zr);
}

// Round 17
// 136.968 us; speedup vs baseline: 5.4417x; 5.4417x over previous
//
#include <hip/hip_runtime.h>
#include <hip/hip_bf16.h>

#define N_NODES 10000
#define NE 160000
#define CAP 96              // direct bucket capacity per (slot,node)
#define SQRT_C 0.1f
#define RINV_SQRT_C 10.0f   // 1/SQRT_C (exact)
#define CC 0.01f
#define EPS 1e-15f
#define MAXNORM ((1.0f - 4e-3f) / SQRT_C)   // geoopt projx boundary, 9.96
#define RMAXNORM (1.0f / MAXNORM)

// R12 postmortem: final_stage VALUBusy=102% (saturated), 0 bank conflicts,
// 0.2% HBM -> pure VALU-throughput-bound. ~25 strict-fp divisions/node
// (~10 inst each) + 4 sqrt Newton chains were ~45% of the issue budget.
// Fix: v_rcp_f32 / v_rsq_f32 (~1e-7 rel err, absorbed by bf16 output floor).
__device__ __forceinline__ float frcp(float x) { return __builtin_amdgcn_rcpf(x); }
__device__ __forceinline__ float frsq(float x) { return __builtin_amdgcn_rsqf(x); }

// fast transcendentals (bounded, sign-known args)
__device__ __forceinline__ float fexp(float x) { return __expf(x); }
__device__ __forceinline__ float ftanh_pos(float x) {      // x >= 0
    return 1.0f - 2.0f * frcp(__expf(2.0f * x) + 1.0f);
}
__device__ __forceinline__ float fatanh01(float t) {       // 0 <= t < 1
    return 0.5f * __logf((1.0f + t) * frcp(1.0f - t));
}

// dual-dtype load: harness may hand float arrays as bf16 or float32
__device__ __forceinline__ float ldf(const void* p, int i, int isbf) {
    return isbf ? __bfloat162float(((const __hip_bfloat16*)p)[i])
                : ((const float*)p)[i];
}

__device__ __forceinline__ int sniff_wave(const void* emb, int tid) {
    unsigned wv = ((const unsigned*)emb)[tid & 63];
    unsigned ex = (wv >> 7) & 0xFFu;
    unsigned long long m = __ballot(ex >= 116u && ex <= 133u);
    return (__popcll(m) >= 32) ? 1 : 0;
}

// ---------- wave-wide helpers (wave64) ----------
__device__ __forceinline__ float wsum(float v) {
#pragma unroll
    for (int off = 32; off > 0; off >>= 1) v += __shfl_xor(v, off, 64);
    return v;
}
__device__ __forceinline__ float wmax(float v) {
#pragma unroll
    for (int off = 32; off > 0; off >>= 1) v = fmaxf(v, __shfl_xor(v, off, 64));
    return v;
}

// DPP wave64 sum (VALU pipe; no ds_bpermute). Total in lane 63 -> readlane.
__device__ __forceinline__ float dpp_wsum(float x) {
    int t;
    t = __builtin_amdgcn_update_dpp(0, __float_as_int(x), 0x111, 0xF, 0xF, true); // row_shr:1
    x += __int_as_float(t);
    t = __builtin_amdgcn_update_dpp(0, __float_as_int(x), 0x112, 0xF, 0xF, true); // row_shr:2
    x += __int_as_float(t);
    t = __builtin_amdgcn_update_dpp(0, __float_as_int(x), 0x114, 0xF, 0xE, true); // row_shr:4
    x += __int_as_float(t);
    t = __builtin_amdgcn_update_dpp(0, __float_as_int(x), 0x118, 0xF, 0xC, true); // row_shr:8
    x += __int_as_float(t);
    t = __builtin_amdgcn_update_dpp(0, __float_as_int(x), 0x142, 0xA, 0xF, true); // row_bcast:15
    x += __int_as_float(t);
    t = __builtin_amdgcn_update_dpp(0, __float_as_int(x), 0x143, 0xC, 0xF, true); // row_bcast:31
    x += __int_as_float(t);
    return __int_as_float(__builtin_amdgcn_readlane(__float_as_int(x), 63));
}

// ---------- kernel 1: node features + direct-bucket scatter + weights ----------
__global__ __launch_bounds__(256) void pre_scatter(const void* __restrict__ emb,
                                                   const void* __restrict__ att_i,
                                                   const void* __restrict__ att_j,
                                                   const void* __restrict__ w1g,
                                                   const void* __restrict__ b1g,
                                                   const void* __restrict__ w2g,
                                                   const void* __restrict__ b2g,
                                                   const int* __restrict__ ei,
                                                   float* __restrict__ xt,
                                                   float* __restrict__ ai,
                                                   float* __restrict__ aj,
                                                   int* __restrict__ cnt,
                                                   unsigned short* __restrict__ bucket,
                                                   int* __restrict__ ovf_cnt,
                                                   unsigned* __restrict__ ovf,
                                                   int* __restrict__ flag,
                                                   float* __restrict__ wf1t,
                                                   float* __restrict__ wf2t,
                                                   float* __restrict__ hb1f,
                                                   float* __restrict__ hb2f,
                                                   float* __restrict__ hbn2) {
    __shared__ int sflag;
    int tid = threadIdx.x;
    int w = tid >> 6, lane = tid & 63;
    if (blockIdx.x < 2500) {
        if (tid < 64) { int s = sniff_wave(emb, tid); if (tid == 0) sflag = s; }
        __syncthreads();
        int isbf = sflag;
        int t = blockIdx.x * 256 + tid;            // 10000*64 threads exact
        int node = t >> 6;
        float u = ldf(emb, node * 64 + lane, isbf);
        // xt = logmap0(projx(expmap0(u))): one wsum, rsq/rcp norm math
        float n2c = fmaxf(wsum(u * u), 1e-30f);
        float rn = frsq(n2c);
        float n = n2c * rn;                        // sqrt(n2)
        float th = ftanh_pos(SQRT_C * n);
        float x0 = th * RINV_SQRT_C * rn * u;      // th/(SQRT_C*n) * u
        float x0n = th * RINV_SQRT_C;
        if (x0n > MAXNORM) { x0 *= MAXNORM * frcp(x0n); x0n = MAXNORM; }
        float tc = fminf(SQRT_C * x0n, 1.0f - 1e-7f);
        float xv = fatanh01(tc) * RINV_SQRT_C * frcp(x0n) * x0;
        xt[node * 64 + lane] = xv;
        float pi = xv * ldf(att_i, lane, isbf);
        float pj = xv * ldf(att_j, lane, isbf);
#pragma unroll
        for (int off = 8; off > 0; off >>= 1) {    // aligned 16-lane head groups
            pi += __shfl_xor(pi, off, 64);
            pj += __shfl_xor(pj, off, 64);
        }
        if ((lane & 15) == 0) {
            ai[node * 4 + (lane >> 4)] = pi;
            aj[node * 4 + (lane >> 4)] = pj;
        }
    } else if (blockIdx.x < 2813) {
        int e0 = (blockIdx.x - 2500) * 512 + tid;  // 313 blocks x 512 edges
#pragma unroll
        for (int q = 0; q < 2; ++q) {
            int e = e0 + q * 256;
            if (e >= NE) break;
            // slot 0 = graph 3, slot 1 = graph 7: independent atomic chains
            int s0 = ei[3 * 2 * NE + e], d0 = ei[3 * 2 * NE + NE + e];
            int s1 = ei[7 * 2 * NE + e], d1 = ei[7 * 2 * NE + NE + e];
            int i0 = s0, i1 = N_NODES + s1;
            int p0 = atomicAdd(&cnt[i0], 1);
            int p1 = atomicAdd(&cnt[i1], 1);
            if (p0 < CAP) bucket[i0 * CAP + p0] = (unsigned short)d0;
            else {
                int oi = atomicAdd(ovf_cnt, 1);    // astronomically rare (deg>96)
                ovf[oi] = (0u << 28) | ((unsigned)s0 << 14) | (unsigned)d0;
            }
            if (p1 < CAP) bucket[i1 * CAP + p1] = (unsigned short)d1;
            else {
                int oi = atomicAdd(ovf_cnt, 1);
                ovf[oi] = (1u << 28) | ((unsigned)s1 << 14) | (unsigned)d1;
            }
        }
    } else {
        if (tid < 64) { int s = sniff_wave(emb, tid); if (tid == 0) sflag = s; }
        __syncthreads();
        int isbf = sflag;
        if (tid == 0) *flag = isbf;                // publish for final_stage
        for (int i = tid; i < 1024; i += 256) {    // w1[o][c] -> wf1t[c*64+o]
            int o = i >> 4, c = i & 15;
            wf1t[c * 64 + o] = ldf(w1g, i, isbf);
        }
        for (int i = tid; i < 4096; i += 256) {    // w2[o][c] -> wf2t[c*64+o]
            int o = i >> 6, c = i & 63;
            wf2t[c * 64 + o] = ldf(w2g, i, isbf);
        }
        if (w < 2) {                               // hb = projx(expmap0(b)), + norm^2
            const void* bg = w ? b2g : b1g;
            float b = ldf(bg, lane, isbf);
            float n2c = fmaxf(wsum(b * b), 1e-30f);
            float rn = frsq(n2c);
            float n = n2c * rn;
            float th = ftanh_pos(SQRT_C * n);
            float hv = th * RINV_SQRT_C * rn * b;
            float hn = th * RINV_SQRT_C;
            if (hn > MAXNORM) { hv *= MAXNORM * frcp(hn); hn = MAXNORM; }
            (w ? hb2f : hb1f)[lane] = hv;
            if (lane == 0) hbn2[w] = hn * hn;
        }
    }
}

// ---------- kernel 2: per-node softmax + aggregation, atomic-free ----------
// sup_t is NODE-MAJOR [20000][16]
__global__ __launch_bounds__(256) void node_agg(const int* __restrict__ cnt,
                                                const unsigned short* __restrict__ bucket,
                                                const int* __restrict__ ovf_cnt,
                                                const unsigned* __restrict__ ovf,
                                                const float* __restrict__ ai,
                                                const float* __restrict__ aj,
                                                const float* __restrict__ xt,
                                                float* __restrict__ sup_t) {
    __shared__ float wlds[4][64 * 4];
    __shared__ int dlds[4][64];
    int w = threadIdx.x >> 6, lane = threadIdx.x & 63;
    int idx = blockIdx.x * 4 + w;          // grid exact: 20000 waves
    int slot = (idx >= N_NODES) ? 1 : 0;
    int n = idx - slot * N_NODES;
    int deg = cnt[idx];
    int start = idx * CAP;

    float4 ai4 = *(const float4*)&ai[n * 4];
    float4 aj4n = *(const float4*)&aj[n * 4];
    float ain[4] = {ai4.x, ai4.y, ai4.z, ai4.w};
    float ajn[4] = {aj4n.x, aj4n.y, aj4n.z, aj4n.w};
    int hh = lane >> 4;
    float acc;

    if (deg <= 63) {
        bool act = (lane <= deg);          // lane==deg is the self-loop
        int d = (lane < deg) ? (int)bucket[start + lane] : n;
        float4 a4 = act ? *(const float4*)&aj[d * 4] : make_float4(0.f, 0.f, 0.f, 0.f);
        float ajv[4] = {a4.x, a4.y, a4.z, a4.w};
        float eh[4];
#pragma unroll
        for (int h = 0; h < 4; ++h) {
            float a = ain[h] + ajv[h];
            a = (a < 0.0f) ? 0.2f * a : a;
            eh[h] = act ? fexp(a) : 0.0f;  // no max-shift needed (bounds)
        }
        float sh[4];
#pragma unroll
        for (int h = 0; h < 4; ++h) sh[h] = wsum(eh[h]);
#pragma unroll
        for (int h = 0; h < 4; ++h)
            wlds[w][lane * 4 + h] = eh[h] * (0.25f * frcp(sh[h] + 1e-16f));
        dlds[w][lane] = d;
        // gather, unrolled x8 with independent accumulators (8 loads in flight)
        int m = deg + 1;
        float s0 = 0.f, s1 = 0.f, s2 = 0.f, s3 = 0.f;
        float s4 = 0.f, s5 = 0.f, s6 = 0.f, s7 = 0.f;
        int e = 0;
        for (; e + 8 <= m; e += 8) {
            int d0 = dlds[w][e],     d1 = dlds[w][e + 1];
            int d2 = dlds[w][e + 2], d3 = dlds[w][e + 3];
            int d4 = dlds[w][e + 4], d5 = dlds[w][e + 5];
            int d6 = dlds[w][e + 6], d7 = dlds[w][e + 7];
            float w0 = wlds[w][(e + 0) * 4 + hh], w1 = wlds[w][(e + 1) * 4 + hh];
            float w2 = wlds[w][(e + 2) * 4 + hh], w3 = wlds[w][(e + 3) * 4 + hh];
            float w4 = wlds[w][(e + 4) * 4 + hh], w5 = wlds[w][(e + 5) * 4 + hh];
            float w6 = wlds[w][(e + 6) * 4 + hh], w7 = wlds[w][(e + 7) * 4 + hh];
            s0 = fmaf(w0, xt[d0 * 64 + lane], s0);
            s1 = fmaf(w1, xt[d1 * 64 + lane], s1);
            s2 = fmaf(w2, xt[d2 * 64 + lane], s2);
            s3 = fmaf(w3, xt[d3 * 64 + lane], s3);
            s4 = fmaf(w4, xt[d4 * 64 + lane], s4);
            s5 = fmaf(w5, xt[d5 * 64 + lane], s5);
            s6 = fmaf(w6, xt[d6 * 64 + lane], s6);
            s7 = fmaf(w7, xt[d7 * 64 + lane], s7);
        }
        for (; e + 4 <= m; e += 4) {
            int d0 = dlds[w][e],     d1 = dlds[w][e + 1];
            int d2 = dlds[w][e + 2], d3 = dlds[w][e + 3];
            float w0 = wlds[w][(e + 0) * 4 + hh], w1 = wlds[w][(e + 1) * 4 + hh];
            float w2 = wlds[w][(e + 2) * 4 + hh], w3 = wlds[w][(e + 3) * 4 + hh];
            s0 = fmaf(w0, xt[d0 * 64 + lane], s0);
            s1 = fmaf(w1, xt[d1 * 64 + lane], s1);
            s2 = fmaf(w2, xt[d2 * 64 + lane], s2);
            s3 = fmaf(w3, xt[d3 * 64 + lane], s3);
        }
        for (; e < m; ++e)
            s0 = fmaf(wlds[w][e * 4 + hh], xt[dlds[w][e] * 64 + lane], s0);
        acc = ((s0 + s1) + (s2 + s3)) + ((s4 + s5) + (s6 + s7));
    } else {
        // slow path (rare): strided over bucket + overflow scan, max-shifted
        int bdeg = (deg < CAP) ? deg : CAP;
        int tov = (deg > CAP) ? *ovf_cnt : 0;
        float mh[4];
#pragma unroll
        for (int h = 0; h < 4; ++h) {
            float a = ain[h] + ajn[h];
            mh[h] = (a < 0.0f) ? 0.2f * a : a;
        }
        for (int e = lane; e < bdeg; e += 64) {
            int d = bucket[start + e];
#pragma unroll
            for (int h = 0; h < 4; ++h) {
                float a = ain[h] + aj[d * 4 + h];
                a = (a < 0.0f) ? 0.2f * a : a;
                mh[h] = fmaxf(mh[h], a);
            }
        }
        for (int k = lane; k < tov; k += 64) {
            unsigned pe = ovf[k];
            if ((int)(pe >> 28) == slot && (int)((pe >> 14) & 0x3FFFu) == n) {
                int d = pe & 0x3FFFu;
#pragma unroll
                for (int h = 0; h < 4; ++h) {
                    float a = ain[h] + aj[d * 4 + h];
                    a = (a < 0.0f) ? 0.2f * a : a;
                    mh[h] = fmaxf(mh[h], a);
                }
            }
        }
#pragma unroll
        for (int h = 0; h < 4; ++h) mh[h] = wmax(mh[h]);
        float sh[4] = {0.f, 0.f, 0.f, 0.f};
        if (lane == 0) {
#pragma unroll
            for (int h = 0; h < 4; ++h) {
                float a = ain[h] + ajn[h];
                a = (a < 0.0f) ? 0.2f * a : a;
                sh[h] = fexp(a - mh[h]);
            }
        }
        for (int e = lane; e < bdeg; e += 64) {
            int d = bucket[start + e];
#pragma unroll
            for (int h = 0; h < 4; ++h) {
                float a = ain[h] + aj[d * 4 + h];
                a = (a < 0.0f) ? 0.2f * a : a;
                sh[h] += fexp(a - mh[h]);
            }
        }
        for (int k = lane; k < tov; k += 64) {
            unsigned pe = ovf[k];
            if ((int)(pe >> 28) == slot && (int)((pe >> 14) & 0x3FFFu) == n) {
                int d = pe & 0x3FFFu;
#pragma unroll
                for (int h = 0; h < 4; ++h) {
                    float a = ain[h] + aj[d * 4 + h];
                    a = (a < 0.0f) ? 0.2f * a : a;
                    sh[h] += fexp(a - mh[h]);
                }
            }
        }
#pragma unroll
        for (int h = 0; h < 4; ++h) sh[h] = wsum(sh[h]);
        float scale[4];
#pragma unroll
        for (int h = 0; h < 4; ++h) scale[h] = 0.25f * frcp(sh[h] + 1e-16f);
        float aih = ain[hh], mhh = mh[hh], sch = scale[hh];
        float aself = aih + ajn[hh];
        aself = (aself < 0.0f) ? 0.2f * aself : aself;
        acc = fexp(aself - mhh) * sch * xt[n * 64 + lane];
        for (int e = 0; e < bdeg; ++e) {
            int d = bucket[start + e];
            float a = aih + aj[d * 4 + hh];
            a = (a < 0.0f) ? 0.2f * a : a;
            acc = fmaf(fexp(a - mhh) * sch, xt[d * 64 + lane], acc);
        }
        for (int k = 0; k < tov; ++k) {
            unsigned pe = ovf[k];
            if ((int)(pe >> 28) == slot && (int)((pe >> 14) & 0x3FFFu) == n) {
                int d = pe & 0x3FFFu;
                float a = aih + aj[d * 4 + hh];
                a = (a < 0.0f) ? 0.2f * a : a;
                acc = fmaf(fexp(a - mhh) * sch, xt[d * 64 + lane], acc);
            }
        }
    }
    acc += __shfl_xor(acc, 16, 64);        // head mean (x0.25 in scale)
    acc += __shfl_xor(acc, 32, 64);
    if (lane < 16) sup_t[idx * 16 + lane] = acc;   // node-major
}

// ---------- kernel 3: DPP hyperbolic head + fast rcp/rsq (R12 fix) ----------
// VALU-bound (R12: VALUBusy 102%); strict-fp divisions were ~45% of issue.
// All x/y -> x*rcp(y); all sqrt+recip pairs -> rsq; /SQRT_C -> *10.
__global__ __launch_bounds__(256) void final_stage(const float* __restrict__ sup_t,
                                                   const float* __restrict__ wf1t,
                                                   const float* __restrict__ wf2t,
                                                   const float* __restrict__ hb1f,
                                                   const float* __restrict__ hb2f,
                                                   const float* __restrict__ hbn2,
                                                   const int* __restrict__ flag,
                                                   void* __restrict__ outv) {
    __shared__ float vz[4][80];            // per-wave scratch: v[16] | z2[64]
    int tid = threadIdx.x, w = tid >> 6, lane = tid & 63;
    float w2r[64];                         // lane o holds W2[o][c], c=0..63
#pragma unroll
    for (int c = 0; c < 64; ++c) w2r[c] = wf2t[c * 64 + lane];
    float w1r[16];
#pragma unroll
    for (int c = 0; c < 16; ++c) w1r[c] = wf1t[c * 64 + lane];
    float hb1 = hb1f[lane], hb2v = hb2f[lane];
    float y2a = hbn2[0], y2b = hbn2[1];
    int isbf = *flag;
    float* vbuf = vz[w];
    float* zbuf = vz[w] + 16;
    int nb = (blockIdx.x * 4 + w) * 4;     // 4 consecutive nodes per wave

    // prefetch all 4 sup rows (independent loads issue together)
    float vls[4];
#pragma unroll
    for (int k = 0; k < 4; ++k)
        vls[k] = (lane < 16) ? sup_t[(nb + k) * 16 + lane] : 0.0f;

#pragma unroll 1
    for (int k = 0; k < 4; ++k) {
        float vl = vls[k];
        if (lane < 16) vbuf[lane] = vl;
        // ---- expmap0 of v ----
        float n2c = fmaxf(dpp_wsum(vl * vl), 1e-30f);
        float rnv = frsq(n2c);
        float n = n2c * rnv;                       // sqrt
        float th0 = ftanh_pos(SQRT_C * n);
        float s0 = th0 * RINV_SQRT_C * rnv;        // th0/(SQRT_C*n)
        float x0n = th0 * RINV_SQRT_C;
        if (x0n > MAXNORM) { s0 *= MAXNORM * frcp(x0n); x0n = MAXNORM; }

        // ---- GEMV1 (16->64): uniform LDS b128 broadcast + reg weights ----
        float a1 = 0.f;
#pragma unroll
        for (int j = 0; j < 4; ++j) {
            const float4 vq = *(const float4*)&vbuf[j * 4];
            a1 = fmaf(w1r[4 * j + 0], vq.x, a1);
            a1 = fmaf(w1r[4 * j + 1], vq.y, a1);
            a1 = fmaf(w1r[4 * j + 2], vq.z, a1);
            a1 = fmaf(w1r[4 * j + 3], vq.w, a1);
        }
        a1 *= s0;                          // scale folded (GEMV linear)

        // ---- mobius_matvec norms + mobius_add (layer 1) ----
        float mxn2 = dpp_wsum(a1 * a1);
        float mxhb = dpp_wsum(a1 * hb1);
        float xn = fmaxf(x0n, EPS);
        float mxc = fmaxf(mxn2, 1e-30f);
        float rmx = frsq(mxc);
        float mxn = mxc * rmx;                     // sqrt
        float t = fminf(SQRT_C * xn, 1.0f - 1e-7f);
        float th = ftanh_pos(mxn * frcp(xn) * fatanh01(t));
        float rs = th * RINV_SQRT_C * rmx;         // th/(mxn*SQRT_C)
        float rn = th * RINV_SQRT_C;
        if (mxn2 == 0.0f) { rs = 0.f; rn = 0.f; }  // all(mx==0) guard
        if (rn > MAXNORM) { rs *= MAXNORM * frcp(rn); rn = MAXNORM; }
        float xy = rs * mxhb;
        float x2 = rn * rn;
        float A = 1.0f + 2.0f * CC * xy + CC * y2a;
        float B = 1.0f - CC * x2;
        float rden = frcp(fmaxf(1.0f + 2.0f * CC * xy + CC * CC * x2 * y2a, EPS));
        float z = (A * rs * a1 + B * hb1) * rden;

        // ---- projx -> logmap0 -> silu ----
        float znc = fmaxf(dpp_wsum(z * z), 1e-30f);
        float rzn = frsq(znc);
        float zn = znc * rzn;
        float sc = (zn > MAXNORM) ? MAXNORM * rzn : 1.0f;
        float z1n = fminf(zn, MAXNORM);
        float rz1n = (zn > MAXNORM) ? RMAXNORM : rzn;   // 1/z1n
        float lg = fatanh01(fminf(SQRT_C * z1n, 1.0f - 1e-7f)) * RINV_SQRT_C * rz1n * sc;
        float u = lg * z;
        u = u * frcp(1.0f + __expf(-u));

        // ---- expmap0 -> projx ----
        float unc = fmaxf(dpp_wsum(u * u), 1e-30f);
        float run = frsq(unc);
        float un = unc * run;
        float th2 = ftanh_pos(SQRT_C * un);
        float s2 = th2 * RINV_SQRT_C * run;
        float z2n = th2 * RINV_SQRT_C;
        if (z2n > MAXNORM) { s2 *= MAXNORM * frcp(z2n); z2n = MAXNORM; }
        float z2 = u * s2;
        // HypDropout eval round-trip == identity -> skip

        // ---- GEMV2 (64->64): LDS roundtrip + uniform b128 + reg weights ----
        zbuf[lane] = z2;
        float a2 = 0.f;
#pragma unroll
        for (int j = 0; j < 16; ++j) {
            const float4 zq = *(const float4*)&zbuf[j * 4];
            a2 = fmaf(w2r[4 * j + 0], zq.x, a2);
            a2 = fmaf(w2r[4 * j + 1], zq.y, a2);
            a2 = fmaf(w2r[4 * j + 2], zq.z, a2);
            a2 = fmaf(w2r[4 * j + 3], zq.w, a2);
        }

        // ---- mobius (layer 2) + final projx ----
        float pn2 = dpp_wsum(a2 * a2);
        float ph2 = dpp_wsum(a2 * hb2v);
        float xnb = fmaxf(z2n, EPS);
        float pnc = fmaxf(pn2, 1e-30f);
        float rpx = frsq(pnc);
        float mxnb = pnc * rpx;
        float tb = fminf(SQRT_C * xnb, 1.0f - 1e-7f);
        float thb = ftanh_pos(mxnb * frcp(xnb) * fatanh01(tb));
        float rsb = thb * RINV_SQRT_C * rpx;
        float rnb = thb * RINV_SQRT_C;
        if (pn2 == 0.0f) { rsb = 0.f; rnb = 0.f; }
        if (rnb > MAXNORM) { rsb *= MAXNORM * frcp(rnb); rnb = MAXNORM; }
        float xyb = rsb * ph2;
        float x2b = rnb * rnb;
        float Ab = 1.0f + 2.0f * CC * xyb + CC * y2b;
        float Bb = 1.0f - CC * x2b;
        float rdenb = frcp(fmaxf(1.0f + 2.0f * CC * xyb + CC * CC * x2b * y2b, EPS));
        float zf = (Ab * rsb * a2 + Bb * hb2v) * rdenb;
        float zfc = fmaxf(dpp_wsum(zf * zf), 1e-30f);
        float rzf = frsq(zfc);
        float znf = zfc * rzf;
        float s4 = (znf > MAXNORM) ? MAXNORM * rzf : 1.0f;
        float val = zf * s4;

        if (isbf) ((__hip_bfloat16*)outv)[(nb + k) * 64 + lane] = __float2bfloat16(val);
        else      ((float*)outv)[(nb + k) * 64 + lane] = val;
    }
}

extern "C" void kernel_launch(void* const* d_in, const int* in_sizes, int n_in,
                              void* d_out, int out_size, void* d_ws, size_t ws_size,
                              hipStream_t stream) {
    // setup_inputs order: history_graphs(0, unused), edge_index(1), emb(2),
    //                     att_i(3), att_j(4), w1(5), b1(6), w2(7), b2(8)
    const int* ei = (const int*)d_in[1];
    const void* emb   = d_in[2];
    const void* att_i = d_in[3];
    const void* att_j = d_in[4];
    const void* w1 = d_in[5];
    const void* b1 = d_in[6];
    const void* w2 = d_in[7];
    const void* b2 = d_in[8];

    // workspace layout (float words), ~9.4 MB total. NO OVERLAPS:
    float* ws = (float*)d_ws;
    float* xt    = ws;                                // [10000][64]: 0..640000
    float* ai    = ws + 640000;                       // [10000][4]
    float* aj    = ws + 680000;                       // [10000][4]
    float* sup_t = ws + 720000;                       // [20000][16]: ..1040000
    int* cnt     = (int*)(ws + 1040000);              // [2][10000]: ..1060000
    int* ovf_cnt = (int*)(ws + 1060000);              // 1 int (memset covers it)
    unsigned short* bucket = (unsigned short*)(ws + 1060032); // ..2020032
    unsigned* ovf = (unsigned*)(ws + 2020032);        // [320000]: ..2340032
    int* flag     = (int*)(ws + 2340032);
    float* wf1t = ws + 2340064;                       // [16][64]: ..2341088
    float* wf2t = ws + 2341088;                       // [64][64]: ..2345184
    float* hb1f = ws + 2345184;                       // [64]
    float* hb2f = ws + 2345248;                       // [64]
    float* hbn2 = ws + 2345312;                       // [2]

    // zero cnt[20000] + ovf_cnt in one 80 KB fill
    hipMemsetAsync((void*)cnt, 0, (2 * N_NODES + 8) * sizeof(int), stream);
    hipLaunchKernelGGL(pre_scatter, dim3(2814), dim3(256), 0, stream,
                       emb, att_i, att_j, w1, b1, w2, b2, ei,
                       xt, ai, aj, cnt, bucket, ovf_cnt, ovf, flag,
                       wf1t, wf2t, hb1f, hb2f, hbn2);
    hipLaunchKernelGGL(node_agg, dim3(5000), dim3(256), 0, stream,
                       cnt, bucket, ovf_cnt, ovf, ai, aj, xt, sup_t);
    hipLaunchKernelGGL(final_stage, dim3(1250), dim3(256), 0, stream,
                       sup_t, wf1t, wf2t, hb1f, hb2f, hbn2, flag, d_out);
}

// Round 19
// 126.996 us; speedup vs baseline: 5.8691x; 1.0785x over previous
//
#include <hip/hip_runtime.h>
#include <hip/hip_bf16.h>

#define N_NODES 10000
#define NE 160000
#define CAP 96              // direct bucket capacity per (slot,node)
#define SQRT_C 0.1f
#define RINV_SQRT_C 10.0f   // 1/SQRT_C (exact)
#define CC 0.01f
#define EPS 1e-15f
#define MAXNORM ((1.0f - 4e-3f) / SQRT_C)   // geoopt projx boundary, 9.96
#define RMAXNORM (1.0f / MAXNORM)

// fast math: R12 showed the head is pure VALU-bound; rcp/rsq verified R17
// (137us, absmax at bf16 floor).
__device__ __forceinline__ float frcp(float x) { return __builtin_amdgcn_rcpf(x); }
__device__ __forceinline__ float frsq(float x) { return __builtin_amdgcn_rsqf(x); }

__device__ __forceinline__ float fexp(float x) { return __expf(x); }
__device__ __forceinline__ float ftanh_pos(float x) {      // x >= 0
    return 1.0f - 2.0f * frcp(__expf(2.0f * x) + 1.0f);
}
__device__ __forceinline__ float fatanh01(float t) {       // 0 <= t < 1
    return 0.5f * __logf((1.0f + t) * frcp(1.0f - t));
}

// dual-dtype load: harness may hand float arrays as bf16 or float32
__device__ __forceinline__ float ldf(const void* p, int i, int isbf) {
    return isbf ? __bfloat162float(((const __hip_bfloat16*)p)[i])
                : ((const float*)p)[i];
}

__device__ __forceinline__ int sniff_wave(const void* emb, int tid) {
    unsigned wv = ((const unsigned*)emb)[tid & 63];
    unsigned ex = (wv >> 7) & 0xFFu;
    unsigned long long m = __ballot(ex >= 116u && ex <= 133u);
    return (__popcll(m) >= 32) ? 1 : 0;
}

// ---------- wave-wide helpers (wave64) ----------
__device__ __forceinline__ float wsum(float v) {
#pragma unroll
    for (int off = 32; off > 0; off >>= 1) v += __shfl_xor(v, off, 64);
    return v;
}
__device__ __forceinline__ float wmax(float v) {
#pragma unroll
    for (int off = 32; off > 0; off >>= 1) v = fmaxf(v, __shfl_xor(v, off, 64));
    return v;
}

// DPP wave64 sum (VALU pipe; no ds_bpermute). Total in lane 63 -> readlane.
__device__ __forceinline__ float dpp_wsum(float x) {
    int t;
    t = __builtin_amdgcn_update_dpp(0, __float_as_int(x), 0x111, 0xF, 0xF, true); // row_shr:1
    x += __int_as_float(t);
    t = __builtin_amdgcn_update_dpp(0, __float_as_int(x), 0x112, 0xF, 0xF, true); // row_shr:2
    x += __int_as_float(t);
    t = __builtin_amdgcn_update_dpp(0, __float_as_int(x), 0x114, 0xF, 0xE, true); // row_shr:4
    x += __int_as_float(t);
    t = __builtin_amdgcn_update_dpp(0, __float_as_int(x), 0x118, 0xF, 0xC, true); // row_shr:8
    x += __int_as_float(t);
    t = __builtin_amdgcn_update_dpp(0, __float_as_int(x), 0x142, 0xA, 0xF, true); // row_bcast:15
    x += __int_as_float(t);
    t = __builtin_amdgcn_update_dpp(0, __float_as_int(x), 0x143, 0xC, 0xF, true); // row_bcast:31
    x += __int_as_float(t);
    return __int_as_float(__builtin_amdgcn_readlane(__float_as_int(x), 63));
}

// ---------- kernel 1: node features + direct-bucket scatter + weights ----------
__global__ __launch_bounds__(256) void pre_scatter(const void* __restrict__ emb,
                                                   const void* __restrict__ att_i,
                                                   const void* __restrict__ att_j,
                                                   const void* __restrict__ w1g,
                                                   const void* __restrict__ b1g,
                                                   const void* __restrict__ w2g,
                                                   const void* __restrict__ b2g,
                                                   const int* __restrict__ ei,
                                                   float* __restrict__ xt,
                                                   float* __restrict__ ai,
                                                   float* __restrict__ aj,
                                                   int* __restrict__ cnt,
                                                   unsigned short* __restrict__ bucket,
                                                   int* __restrict__ ovf_cnt,
                                                   unsigned* __restrict__ ovf,
                                                   int* __restrict__ flag,
                                                   float* __restrict__ wf1t,
                                                   float* __restrict__ wf2t,
                                                   float* __restrict__ hb1f,
                                                   float* __restrict__ hb2f,
                                                   float* __restrict__ hbn2) {
    __shared__ int sflag;
    int tid = threadIdx.x;
    int w = tid >> 6, lane = tid & 63;
    if (blockIdx.x < 2500) {
        if (tid < 64) { int s = sniff_wave(emb, tid); if (tid == 0) sflag = s; }
        __syncthreads();
        int isbf = sflag;
        int t = blockIdx.x * 256 + tid;            // 10000*64 threads exact
        int node = t >> 6;
        float u = ldf(emb, node * 64 + lane, isbf);
        // xt = logmap0(projx(expmap0(u))): one wsum, rsq/rcp norm math
        float n2c = fmaxf(wsum(u * u), 1e-30f);
        float rn = frsq(n2c);
        float n = n2c * rn;                        // sqrt(n2)
        float th = ftanh_pos(SQRT_C * n);
        float x0 = th * RINV_SQRT_C * rn * u;      // th/(SQRT_C*n) * u
        float x0n = th * RINV_SQRT_C;
        if (x0n > MAXNORM) { x0 *= MAXNORM * frcp(x0n); x0n = MAXNORM; }
        float tc = fminf(SQRT_C * x0n, 1.0f - 1e-7f);
        float xv = fatanh01(tc) * RINV_SQRT_C * frcp(x0n) * x0;
        xt[node * 64 + lane] = xv;
        float pi = xv * ldf(att_i, lane, isbf);
        float pj = xv * ldf(att_j, lane, isbf);
#pragma unroll
        for (int off = 8; off > 0; off >>= 1) {    // aligned 16-lane head groups
            pi += __shfl_xor(pi, off, 64);
            pj += __shfl_xor(pj, off, 64);
        }
        if ((lane & 15) == 0) {
            ai[node * 4 + (lane >> 4)] = pi;
            aj[node * 4 + (lane >> 4)] = pj;
        }
    } else if (blockIdx.x < 2813) {
        int e0 = (blockIdx.x - 2500) * 512 + tid;  // 313 blocks x 512 edges
#pragma unroll
        for (int q = 0; q < 2; ++q) {
            int e = e0 + q * 256;
            if (e >= NE) break;
            // slot 0 = graph 3, slot 1 = graph 7: independent atomic chains
            int s0 = ei[3 * 2 * NE + e], d0 = ei[3 * 2 * NE + NE + e];
            int s1 = ei[7 * 2 * NE + e], d1 = ei[7 * 2 * NE + NE + e];
            int i0 = s0, i1 = N_NODES + s1;
            int p0 = atomicAdd(&cnt[i0], 1);
            int p1 = atomicAdd(&cnt[i1], 1);
            if (p0 < CAP) bucket[i0 * CAP + p0] = (unsigned short)d0;
            else {
                int oi = atomicAdd(ovf_cnt, 1);    // astronomically rare (deg>96)
                ovf[oi] = (0u << 28) | ((unsigned)s0 << 14) | (unsigned)d0;
            }
            if (p1 < CAP) bucket[i1 * CAP + p1] = (unsigned short)d1;
            else {
                int oi = atomicAdd(ovf_cnt, 1);
                ovf[oi] = (1u << 28) | ((unsigned)s1 << 14) | (unsigned)d1;
            }
        }
    } else {
        if (tid < 64) { int s = sniff_wave(emb, tid); if (tid == 0) sflag = s; }
        __syncthreads();
        int isbf = sflag;
        if (tid == 0) *flag = isbf;                // publish for agg_head
        for (int i = tid; i < 1024; i += 256) {    // w1[o][c] -> wf1t[c*64+o]
            int o = i >> 4, c = i & 15;
            wf1t[c * 64 + o] = ldf(w1g, i, isbf);
        }
        for (int i = tid; i < 4096; i += 256) {    // w2[o][c] -> wf2t[c*64+o]
            int o = i >> 6, c = i & 63;
            wf2t[c * 64 + o] = ldf(w2g, i, isbf);
        }
        if (w < 2) {                               // hb = projx(expmap0(b)), + norm^2
            const void* bg = w ? b2g : b1g;
            float b = ldf(bg, lane, isbf);
            float n2c = fmaxf(wsum(b * b), 1e-30f);
            float rn = frsq(n2c);
            float n = n2c * rn;
            float th = ftanh_pos(SQRT_C * n);
            float hv = th * RINV_SQRT_C * rn * b;
            float hn = th * RINV_SQRT_C;
            if (hn > MAXNORM) { hv *= MAXNORM * frcp(hn); hn = MAXNORM; }
            (w ? hb2f : hb1f)[lane] = hv;
            if (lane == 0) hbn2[w] = hn * hn;
        }
    }
}

// ---------- kernel 2: aggregation + FUSED hyperbolic head (R17 fusion) ----------
// R12/R17: final_stage standalone cost ~25-28us cold for only ~15us of VALU
// work. After node_agg's two shfl folds, EVERY lane holds v[lane&15] in a
// register -> the head's input is register-resident; sup_t and the third
// kernel are deleted. Head body = R17-verified final_stage with
// n2 = 0.25*dpp(v^2) (4 exact replicas) and W1/W2 streamed from L2-hot
// wf1t/wf2t inside the FMA loops (short live ranges, occupancy preserved).
__global__ __launch_bounds__(256) void agg_head(const int* __restrict__ cnt,
                                                const unsigned short* __restrict__ bucket,
                                                const int* __restrict__ ovf_cnt,
                                                const unsigned* __restrict__ ovf,
                                                const float* __restrict__ ai,
                                                const float* __restrict__ aj,
                                                const float* __restrict__ xt,
                                                const float* __restrict__ wf1t,
                                                const float* __restrict__ wf2t,
                                                const float* __restrict__ hb1f,
                                                const float* __restrict__ hb2f,
                                                const float* __restrict__ hbn2,
                                                const int* __restrict__ flag,
                                                void* __restrict__ outv) {
    __shared__ float wlds[4][64 * 4];
    __shared__ int dlds[4][64];
    int w = threadIdx.x >> 6, lane = threadIdx.x & 63;
    int idx = blockIdx.x * 4 + w;          // grid exact: 20000 waves
    int slot = (idx >= N_NODES) ? 1 : 0;
    int n = idx - slot * N_NODES;
    int deg = cnt[idx];
    int start = idx * CAP;

    float4 ai4 = *(const float4*)&ai[n * 4];
    float4 aj4n = *(const float4*)&aj[n * 4];
    float ain[4] = {ai4.x, ai4.y, ai4.z, ai4.w};
    float ajn[4] = {aj4n.x, aj4n.y, aj4n.z, aj4n.w};
    int hh = lane >> 4;
    float acc;

    if (deg <= 63) {
        bool act = (lane <= deg);          // lane==deg is the self-loop
        int d = (lane < deg) ? (int)bucket[start + lane] : n;
        float4 a4 = act ? *(const float4*)&aj[d * 4] : make_float4(0.f, 0.f, 0.f, 0.f);
        float ajv[4] = {a4.x, a4.y, a4.z, a4.w};
        float eh[4];
#pragma unroll
        for (int h = 0; h < 4; ++h) {
            float a = ain[h] + ajv[h];
            a = (a < 0.0f) ? 0.2f * a : a;
            eh[h] = act ? fexp(a) : 0.0f;  // no max-shift needed (bounds)
        }
        float sh[4];
#pragma unroll
        for (int h = 0; h < 4; ++h) sh[h] = wsum(eh[h]);
#pragma unroll
        for (int h = 0; h < 4; ++h)
            wlds[w][lane * 4 + h] = eh[h] * (0.25f * frcp(sh[h] + 1e-16f));
        dlds[w][lane] = d;
        // gather, unrolled x8 with independent accumulators (8 loads in flight)
        int m = deg + 1;
        float s0 = 0.f, s1 = 0.f, s2 = 0.f, s3 = 0.f;
        float s4 = 0.f, s5 = 0.f, s6 = 0.f, s7 = 0.f;
        int e = 0;
        for (; e + 8 <= m; e += 8) {
            int d0 = dlds[w][e],     d1 = dlds[w][e + 1];
            int d2 = dlds[w][e + 2], d3 = dlds[w][e + 3];
            int d4 = dlds[w][e + 4], d5 = dlds[w][e + 5];
            int d6 = dlds[w][e + 6], d7 = dlds[w][e + 7];
            float w0 = wlds[w][(e + 0) * 4 + hh], w1 = wlds[w][(e + 1) * 4 + hh];
            float w2 = wlds[w][(e + 2) * 4 + hh], w3 = wlds[w][(e + 3) * 4 + hh];
            float w4 = wlds[w][(e + 4) * 4 + hh], w5 = wlds[w][(e + 5) * 4 + hh];
            float w6 = wlds[w][(e + 6) * 4 + hh], w7 = wlds[w][(e + 7) * 4 + hh];
            s0 = fmaf(w0, xt[d0 * 64 + lane], s0);
            s1 = fmaf(w1, xt[d1 * 64 + lane], s1);
            s2 = fmaf(w2, xt[d2 * 64 + lane], s2);
            s3 = fmaf(w3, xt[d3 * 64 + lane], s3);
            s4 = fmaf(w4, xt[d4 * 64 + lane], s4);
            s5 = fmaf(w5, xt[d5 * 64 + lane], s5);
            s6 = fmaf(w6, xt[d6 * 64 + lane], s6);
            s7 = fmaf(w7, xt[d7 * 64 + lane], s7);
        }
        for (; e + 4 <= m; e += 4) {
            int d0 = dlds[w][e],     d1 = dlds[w][e + 1];
            int d2 = dlds[w][e + 2], d3 = dlds[w][e + 3];
            float w0 = wlds[w][(e + 0) * 4 + hh], w1 = wlds[w][(e + 1) * 4 + hh];
            float w2 = wlds[w][(e + 2) * 4 + hh], w3 = wlds[w][(e + 3) * 4 + hh];
            s0 = fmaf(w0, xt[d0 * 64 + lane], s0);
            s1 = fmaf(w1, xt[d1 * 64 + lane], s1);
            s2 = fmaf(w2, xt[d2 * 64 + lane], s2);
            s3 = fmaf(w3, xt[d3 * 64 + lane], s3);
        }
        for (; e < m; ++e)
            s0 = fmaf(wlds[w][e * 4 + hh], xt[dlds[w][e] * 64 + lane], s0);
        acc = ((s0 + s1) + (s2 + s3)) + ((s4 + s5) + (s6 + s7));
    } else {
        // slow path (rare): strided over bucket + overflow scan, max-shifted
        int bdeg = (deg < CAP) ? deg : CAP;
        int tov = (deg > CAP) ? *ovf_cnt : 0;
        float mh[4];
#pragma unroll
        for (int h = 0; h < 4; ++h) {
            float a = ain[h] + ajn[h];
            mh[h] = (a < 0.0f) ? 0.2f * a : a;
        }
        for (int e = lane; e < bdeg; e += 64) {
            int d = bucket[start + e];
#pragma unroll
            for (int h = 0; h < 4; ++h) {
                float a = ain[h] + aj[d * 4 + h];
                a = (a < 0.0f) ? 0.2f * a : a;
                mh[h] = fmaxf(mh[h], a);
            }
        }
        for (int k = lane; k < tov; k += 64) {
            unsigned pe = ovf[k];
            if ((int)(pe >> 28) == slot && (int)((pe >> 14) & 0x3FFFu) == n) {
                int d = pe & 0x3FFFu;
#pragma unroll
                for (int h = 0; h < 4; ++h) {
                    float a = ain[h] + aj[d * 4 + h];
                    a = (a < 0.0f) ? 0.2f * a : a;
                    mh[h] = fmaxf(mh[h], a);
                }
            }
        }
#pragma unroll
        for (int h = 0; h < 4; ++h) mh[h] = wmax(mh[h]);
        float sh[4] = {0.f, 0.f, 0.f, 0.f};
        if (lane == 0) {
#pragma unroll
            for (int h = 0; h < 4; ++h) {
                float a = ain[h] + ajn[h];
                a = (a < 0.0f) ? 0.2f * a : a;
                sh[h] = fexp(a - mh[h]);
            }
        }
        for (int e = lane; e < bdeg; e += 64) {
            int d = bucket[start + e];
#pragma unroll
            for (int h = 0; h < 4; ++h) {
                float a = ain[h] + aj[d * 4 + h];
                a = (a < 0.0f) ? 0.2f * a : a;
                sh[h] += fexp(a - mh[h]);
            }
        }
        for (int k = lane; k < tov; k += 64) {
            unsigned pe = ovf[k];
            if ((int)(pe >> 28) == slot && (int)((pe >> 14) & 0x3FFFu) == n) {
                int d = pe & 0x3FFFu;
#pragma unroll
                for (int h = 0; h < 4; ++h) {
                    float a = ain[h] + aj[d * 4 + h];
                    a = (a < 0.0f) ? 0.2f * a : a;
                    sh[h] += fexp(a - mh[h]);
                }
            }
        }
#pragma unroll
        for (int h = 0; h < 4; ++h) sh[h] = wsum(sh[h]);
        float scale[4];
#pragma unroll
        for (int h = 0; h < 4; ++h) scale[h] = 0.25f * frcp(sh[h] + 1e-16f);
        float aih = ain[hh], mhh = mh[hh], sch = scale[hh];
        float aself = aih + ajn[hh];
        aself = (aself < 0.0f) ? 0.2f * aself : aself;
        acc = fexp(aself - mhh) * sch * xt[n * 64 + lane];
        for (int e = 0; e < bdeg; ++e) {
            int d = bucket[start + e];
            float a = aih + aj[d * 4 + hh];
            a = (a < 0.0f) ? 0.2f * a : a;
            acc = fmaf(fexp(a - mhh) * sch, xt[d * 64 + lane], acc);
        }
        for (int k = 0; k < tov; ++k) {
            unsigned pe = ovf[k];
            if ((int)(pe >> 28) == slot && (int)((pe >> 14) & 0x3FFFu) == n) {
                int d = pe & 0x3FFFu;
                float a = aih + aj[d * 4 + hh];
                a = (a < 0.0f) ? 0.2f * a : a;
                acc = fmaf(fexp(a - mhh) * sch, xt[d * 64 + lane], acc);
            }
        }
    }
    acc += __shfl_xor(acc, 16, 64);        // head mean (x0.25 in scale)
    acc += __shfl_xor(acc, 32, 64);        // now ALL lanes hold v[lane&15]

    // ---------- fused hyperbolic head (R17 final_stage body) ----------
    float vl = acc;
    float* vbuf = wlds[w];                 // softmax scratch is free now
    float* zbuf = wlds[w] + 16;
    if (lane < 16) vbuf[lane] = vl;
    int isbf = *flag;
    float y2a = hbn2[0], y2b = hbn2[1];
    float hb1 = hb1f[lane], hb2v = hb2f[lane];

    // ---- expmap0 of v (4 exact replicas per channel -> x0.25) ----
    float n2c = fmaxf(0.25f * dpp_wsum(vl * vl), 1e-30f);
    float rnv = frsq(n2c);
    float nn = n2c * rnv;                  // sqrt
    float th0 = ftanh_pos(SQRT_C * nn);
    float s0v = th0 * RINV_SQRT_C * rnv;   // th0/(SQRT_C*n)
    float x0n = th0 * RINV_SQRT_C;
    if (x0n > MAXNORM) { s0v *= MAXNORM * frcp(x0n); x0n = MAXNORM; }

    // ---- GEMV1 (16->64): uniform LDS b128 broadcast + streamed W1 ----
    float a1 = 0.f;
#pragma unroll
    for (int j = 0; j < 4; ++j) {
        const float4 vq = *(const float4*)&vbuf[j * 4];
        a1 = fmaf(wf1t[(4 * j + 0) * 64 + lane], vq.x, a1);
        a1 = fmaf(wf1t[(4 * j + 1) * 64 + lane], vq.y, a1);
        a1 = fmaf(wf1t[(4 * j + 2) * 64 + lane], vq.z, a1);
        a1 = fmaf(wf1t[(4 * j + 3) * 64 + lane], vq.w, a1);
    }
    a1 *= s0v;                             // scale folded (GEMV linear)

    // ---- mobius_matvec norms + mobius_add (layer 1) ----
    float mxn2 = dpp_wsum(a1 * a1);
    float mxhb = dpp_wsum(a1 * hb1);
    float xn = fmaxf(x0n, EPS);
    float mxc = fmaxf(mxn2, 1e-30f);
    float rmx = frsq(mxc);
    float mxn = mxc * rmx;                 // sqrt
    float t = fminf(SQRT_C * xn, 1.0f - 1e-7f);
    float th = ftanh_pos(mxn * frcp(xn) * fatanh01(t));
    float rs = th * RINV_SQRT_C * rmx;     // th/(mxn*SQRT_C)
    float rn = th * RINV_SQRT_C;
    if (mxn2 == 0.0f) { rs = 0.f; rn = 0.f; }   // all(mx==0) guard
    if (rn > MAXNORM) { rs *= MAXNORM * frcp(rn); rn = MAXNORM; }
    float xy = rs * mxhb;
    float x2 = rn * rn;
    float A = 1.0f + 2.0f * CC * xy + CC * y2a;
    float B = 1.0f - CC * x2;
    float rden = frcp(fmaxf(1.0f + 2.0f * CC * xy + CC * CC * x2 * y2a, EPS));
    float z = (A * rs * a1 + B * hb1) * rden;

    // ---- projx -> logmap0 -> silu ----
    float znc = fmaxf(dpp_wsum(z * z), 1e-30f);
    float rzn = frsq(znc);
    float zn = znc * rzn;
    float scz = (zn > MAXNORM) ? MAXNORM * rzn : 1.0f;
    float z1n = fminf(zn, MAXNORM);
    float rz1n = (zn > MAXNORM) ? RMAXNORM : rzn;    // 1/z1n
    float lg = fatanh01(fminf(SQRT_C * z1n, 1.0f - 1e-7f)) * RINV_SQRT_C * rz1n * scz;
    float u = lg * z;
    u = u * frcp(1.0f + __expf(-u));

    // ---- expmap0 -> projx ----
    float unc = fmaxf(dpp_wsum(u * u), 1e-30f);
    float run = frsq(unc);
    float un = unc * run;
    float th2 = ftanh_pos(SQRT_C * un);
    float s2 = th2 * RINV_SQRT_C * run;
    float z2n = th2 * RINV_SQRT_C;
    if (z2n > MAXNORM) { s2 *= MAXNORM * frcp(z2n); z2n = MAXNORM; }
    float z2 = u * s2;
    // HypDropout eval round-trip == identity -> skip

    // ---- GEMV2 (64->64): LDS roundtrip + uniform b128 + streamed W2 ----
    zbuf[lane] = z2;
    float a2 = 0.f;
#pragma unroll
    for (int j = 0; j < 16; ++j) {
        const float4 zq = *(const float4*)&zbuf[j * 4];
        a2 = fmaf(wf2t[(4 * j + 0) * 64 + lane], zq.x, a2);
        a2 = fmaf(wf2t[(4 * j + 1) * 64 + lane], zq.y, a2);
        a2 = fmaf(wf2t[(4 * j + 2) * 64 + lane], zq.z, a2);
        a2 = fmaf(wf2t[(4 * j + 3) * 64 + lane], zq.w, a2);
    }

    // ---- mobius (layer 2) + final projx ----
    float pn2 = dpp_wsum(a2 * a2);
    float ph2 = dpp_wsum(a2 * hb2v);
    float xnb = fmaxf(z2n, EPS);
    float pnc = fmaxf(pn2, 1e-30f);
    float rpx = frsq(pnc);
    float mxnb = pnc * rpx;
    float tb = fminf(SQRT_C * xnb, 1.0f - 1e-7f);
    float thb = ftanh_pos(mxnb * frcp(xnb) * fatanh01(tb));
    float rsb = thb * RINV_SQRT_C * rpx;
    float rnb = thb * RINV_SQRT_C;
    if (pn2 == 0.0f) { rsb = 0.f; rnb = 0.f; }
    if (rnb > MAXNORM) { rsb *= MAXNORM * frcp(rnb); rnb = MAXNORM; }
    float xyb = rsb * ph2;
    float x2b = rnb * rnb;
    float Ab = 1.0f + 2.0f * CC * xyb + CC * y2b;
    float Bb = 1.0f - CC * x2b;
    float rdenb = frcp(fmaxf(1.0f + 2.0f * CC * xyb + CC * CC * x2b * y2b, EPS));
    float zf = (Ab * rsb * a2 + Bb * hb2v) * rdenb;
    float zfc = fmaxf(dpp_wsum(zf * zf), 1e-30f);
    float rzf = frsq(zfc);
    float znf = zfc * rzf;
    float s4 = (znf > MAXNORM) ? MAXNORM * rzf : 1.0f;
    float val = zf * s4;

    if (isbf) ((__hip_bfloat16*)outv)[idx * 64 + lane] = __float2bfloat16(val);
    else      ((float*)outv)[idx * 64 + lane] = val;
}

extern "C" void kernel_launch(void* const* d_in, const int* in_sizes, int n_in,
                              void* d_out, int out_size, void* d_ws, size_t ws_size,
                              hipStream_t stream) {
    // setup_inputs order: history_graphs(0, unused), edge_index(1), emb(2),
    //                     att_i(3), att_j(4), w1(5), b1(6), w2(7), b2(8)
    const int* ei = (const int*)d_in[1];
    const void* emb   = d_in[2];
    const void* att_i = d_in[3];
    const void* att_j = d_in[4];
    const void* w1 = d_in[5];
    const void* b1 = d_in[6];
    const void* w2 = d_in[7];
    const void* b2 = d_in[8];

    // workspace layout (float words), ~9.4 MB total. NO OVERLAPS
    // (sup_t region retired by the R17 fusion; slot kept for layout stability)
    float* ws = (float*)d_ws;
    float* xt    = ws;                                // [10000][64]: 0..640000
    float* ai    = ws + 640000;                       // [10000][4]
    float* aj    = ws + 680000;                       // [10000][4]
    int* cnt     = (int*)(ws + 1040000);              // [2][10000]: ..1060000
    int* ovf_cnt = (int*)(ws + 1060000);              // 1 int (memset covers it)
    unsigned short* bucket = (unsigned short*)(ws + 1060032); // ..2020032
    unsigned* ovf = (unsigned*)(ws + 2020032);        // [320000]: ..2340032
    int* flag     = (int*)(ws + 2340032);
    float* wf1t = ws + 2340064;                       // [16][64]: ..2341088
    float* wf2t = ws + 2341088;                       // [64][64]: ..2345184
    float* hb1f = ws + 2345184;                       // [64]
    float* hb2f = ws + 2345248;                       // [64]
    float* hbn2 = ws + 2345312;                       // [2]

    // zero cnt[20000] + ovf_cnt in one 80 KB fill
    hipMemsetAsync((void*)cnt, 0, (2 * N_NODES + 8) * sizeof(int), stream);
    hipLaunchKernelGGL(pre_scatter, dim3(2814), dim3(256), 0, stream,
                       emb, att_i, att_j, w1, b1, w2, b2, ei,
                       xt, ai, aj, cnt, bucket, ovf_cnt, ovf, flag,
                       wf1t, wf2t, hb1f, hb2f, hbn2);
    hipLaunchKernelGGL(agg_head, dim3(5000), dim3(256), 0, stream,
                       cnt, bucket, ovf_cnt, ovf, ai, aj, xt,
                       wf1t, wf2t, hb1f, hb2f, hbn2, flag, d_out);
}